// Round 1
// baseline (390.224 us; speedup 1.0000x reference)
//
#include <hip/hip_runtime.h>
#include <hip/hip_bf16.h>
#include <stdint.h>

// dims (fixed by the problem)
#define T_TOK 4096
#define NE    8
#define DM    1024
#define FF    4096
#define CAP   1536

typedef __attribute__((ext_vector_type(8))) __bf16 bf16x8;
typedef __attribute__((ext_vector_type(4))) float  f32x4;

__device__ __forceinline__ void gload_lds16(const void* gptr, void* lptr) {
  __builtin_amdgcn_global_load_lds(
      (__attribute__((address_space(1))) void*)(uintptr_t)gptr,
      (__attribute__((address_space(3))) void*)(uintptr_t)lptr,
      16, 0, 0);
}

// ---------------- small prep kernels ----------------

__global__ void conv_x_kernel(const float4* __restrict__ src, ushort4* __restrict__ dst, int n4) {
  int i = blockIdx.x * blockDim.x + threadIdx.x;
  if (i >= n4) return;
  float4 v = src[i];
  ushort4 o;
  o.x = __builtin_bit_cast(unsigned short, __float2bfloat16(v.x));
  o.y = __builtin_bit_cast(unsigned short, __float2bfloat16(v.y));
  o.z = __builtin_bit_cast(unsigned short, __float2bfloat16(v.z));
  o.w = __builtin_bit_cast(unsigned short, __float2bfloat16(v.w));
  dst[i] = o;
}

// transpose+convert: src f32 [B][R][C] -> dst bf16 [B][C][R]
__global__ void tconv_kernel(const float* __restrict__ src, __hip_bfloat16* __restrict__ dst,
                             int R, int C) {
  __shared__ float tile[32][33];
  const int b  = blockIdx.z;
  const int r0 = blockIdx.y * 32;
  const int c0 = blockIdx.x * 32;
  const float* s = src + (size_t)b * R * C;
  __hip_bfloat16* d = dst + (size_t)b * R * C;
  const int tx = threadIdx.x, ty = threadIdx.y;
#pragma unroll
  for (int rr = ty; rr < 32; rr += 8)
    tile[rr][tx] = s[(size_t)(r0 + rr) * C + c0 + tx];
  __syncthreads();
#pragma unroll
  for (int cc = ty; cc < 32; cc += 8)
    d[(size_t)(c0 + cc) * R + r0 + tx] = __float2bfloat16(tile[tx][cc]);
}

__global__ void router_kernel(const float* __restrict__ rw, int* __restrict__ counts,
                              int* __restrict__ tok_ids, float* __restrict__ gains) {
  int t = blockIdx.x * blockDim.x + threadIdx.x;
  if (t >= T_TOK) return;
#pragma unroll
  for (int e = 0; e < NE; ++e) {
    float w = rw[t * NE + e];
    if (w > 0.f) {
      int pos = atomicAdd(&counts[e], 1);
      if (pos < CAP) {
        tok_ids[e * CAP + pos] = t;
        gains[e * CAP + pos]   = w;
      }
    }
  }
}

__global__ void pad_kernel(const int* __restrict__ counts, int* __restrict__ tok_ids,
                           float* __restrict__ gains) {
  int i = blockIdx.x * blockDim.x + threadIdx.x;
  if (i >= NE * CAP) return;
  int e = i / CAP, pos = i % CAP;
  int ne = min(counts[e], CAP);
  if (pos >= ne) { tok_ids[i] = 0; gains[i] = 0.f; }
}

// ---------------- grouped MFMA GEMM ----------------
// PASS 1:  H[e,c,:FF] = relu( gather(x)[c,:DM] @ W1t[e]^T + b1[e] )   (bf16 out)
// PASS 2:  y[tok(c)] += gain * ( H[e,c,:FF] @ W2t[e]^T + b2[e] )       (atomic f32)
// Tiles: BM=BN=128, BK=32, 256 threads (4 waves, 2x2 of 64x64), mfma 16x16x32 bf16.

template <int PASS>
__global__ __launch_bounds__(256, 2)
void moe_gemm(const __hip_bfloat16* __restrict__ Asrc,
              const __hip_bfloat16* __restrict__ Bsrc,   // [E][NP][K] (B^T, k contiguous)
              const float* __restrict__ bias,            // [E][NP]
              const int* __restrict__ counts,
              const int* __restrict__ tok_ids,
              const float* __restrict__ gains,
              __hip_bfloat16* __restrict__ Hout,         // PASS1 out [E][CAP][FF]
              float* __restrict__ y)                     // PASS2 out [T][DM]
{
  constexpr int K  = (PASS == 1) ? DM : FF;
  constexpr int NP = (PASS == 1) ? FF : DM;
  constexpr int MT = CAP / 128;  // 12
  constexpr int NT = NP / 128;

  const int bid = blockIdx.x;
  const int e   = bid / (MT * NT);
  const int rem = bid % (MT * NT);
  const int mt  = rem / NT;
  const int nt  = rem % NT;

  const int Ne = min(counts[e], CAP);
  const int m0 = mt * 128;
  if (m0 >= Ne) return;
  const int n0 = nt * 128;

  __shared__ alignas(16) __hip_bfloat16 As[128 * 32];
  __shared__ alignas(16) __hip_bfloat16 Bs[128 * 32];

  const int tid  = threadIdx.x;
  const int lane = tid & 63;
  const int wid  = tid >> 6;
  const int wm   = wid >> 1;
  const int wn   = wid & 1;

  // staging: tile is 512 chunks of 16B; chunk c = l*256+tid -> row=c>>2, kchunk=c&3
  const int srow0 = tid >> 2;
  const int srow1 = 64 + (tid >> 2);
  const int schk  = (tid & 3) * 8;  // k offset in elements

  const __hip_bfloat16 *aptr0, *aptr1;
  if (PASS == 1) {
    const int tok0 = tok_ids[e * CAP + m0 + srow0];
    const int tok1 = tok_ids[e * CAP + m0 + srow1];
    aptr0 = Asrc + (size_t)tok0 * DM + schk;
    aptr1 = Asrc + (size_t)tok1 * DM + schk;
  } else {
    aptr0 = Asrc + ((size_t)e * CAP + m0 + srow0) * FF + schk;
    aptr1 = Asrc + ((size_t)e * CAP + m0 + srow1) * FF + schk;
  }
  const __hip_bfloat16* bptr0 = Bsrc + ((size_t)e * NP + n0 + srow0) * K + schk;
  const __hip_bfloat16* bptr1 = Bsrc + ((size_t)e * NP + n0 + srow1) * K + schk;

  char* asw0 = (char*)As + wid * 1024;
  char* asw1 = (char*)As + 4096 + wid * 1024;
  char* bsw0 = (char*)Bs + wid * 1024;
  char* bsw1 = (char*)Bs + 4096 + wid * 1024;

  const char* AsB = (const char*)As;
  const char* BsB = (const char*)Bs;
  const int fr = lane & 15;
  const int fq = lane >> 4;
  const int koffB = fq * 16;  // byte offset of this lane's 8-elem k-slice

  f32x4 acc[4][4] = {};

  for (int k0 = 0; k0 < K; k0 += 32) {
    gload_lds16(aptr0, asw0);
    gload_lds16(aptr1, asw1);
    gload_lds16(bptr0, bsw0);
    gload_lds16(bptr1, bsw1);
    aptr0 += 32; aptr1 += 32; bptr0 += 32; bptr1 += 32;
    __syncthreads();

    bf16x8 af[4], bfr[4];
#pragma unroll
    for (int i = 0; i < 4; ++i)
      af[i] = *(const bf16x8*)(AsB + (wm * 64 + i * 16 + fr) * 64 + koffB);
#pragma unroll
    for (int j = 0; j < 4; ++j)
      bfr[j] = *(const bf16x8*)(BsB + (wn * 64 + j * 16 + fr) * 64 + koffB);
#pragma unroll
    for (int i = 0; i < 4; ++i)
#pragma unroll
      for (int j = 0; j < 4; ++j)
        acc[i][j] = __builtin_amdgcn_mfma_f32_16x16x32_bf16(af[i], bfr[j], acc[i][j], 0, 0, 0);
    __syncthreads();
  }

  const int colb = n0 + wn * 64 + fr;
  if (PASS == 1) {
#pragma unroll
    for (int j = 0; j < 4; ++j) {
      const float bv = bias[(size_t)e * NP + colb + j * 16];
#pragma unroll
      for (int i = 0; i < 4; ++i)
#pragma unroll
        for (int rr = 0; rr < 4; ++rr) {
          const int row = m0 + wm * 64 + i * 16 + fq * 4 + rr;
          float v = acc[i][j][rr] + bv;
          v = v > 0.f ? v : 0.f;
          Hout[((size_t)e * CAP + row) * FF + colb + j * 16] = __float2bfloat16(v);
        }
    }
  } else {
    float bv[4];
#pragma unroll
    for (int j = 0; j < 4; ++j) bv[j] = bias[(size_t)e * NP + colb + j * 16];
#pragma unroll
    for (int i = 0; i < 4; ++i)
#pragma unroll
      for (int rr = 0; rr < 4; ++rr) {
        const int row  = m0 + wm * 64 + i * 16 + fq * 4 + rr;
        const int slot = e * CAP + row;
        const float g  = gains[slot];
        if (g != 0.f) {
          const int tok = tok_ids[slot];
          float* yrow = y + (size_t)tok * DM + colb;
#pragma unroll
          for (int j = 0; j < 4; ++j)
            atomicAdd(yrow + j * 16, (acc[i][j][rr] + bv[j]) * g);
        }
      }
  }
}

// ---------------- launch ----------------

extern "C" void kernel_launch(void* const* d_in, const int* in_sizes, int n_in,
                              void* d_out, int out_size, void* d_ws, size_t ws_size,
                              hipStream_t stream) {
  const float* x  = (const float*)d_in[0];
  // d_in[1] = route_mask (bool) — unused: mask == (route_weight > 0)
  const float* rw = (const float*)d_in[2];
  const float* W1 = (const float*)d_in[3];
  const float* b1 = (const float*)d_in[4];
  const float* W2 = (const float*)d_in[5];
  const float* b2 = (const float*)d_in[6];
  float* y = (float*)d_out;

  char* ws = (char*)d_ws;
  size_t off = 0;
  auto alloc = [&](size_t bytes) {
    void* p = ws + off;
    off = (off + bytes + 255) & ~(size_t)255;
    return p;
  };
  __hip_bfloat16* xb  = (__hip_bfloat16*)alloc((size_t)T_TOK * DM * 2);       // 8.4 MB
  __hip_bfloat16* w1t = (__hip_bfloat16*)alloc((size_t)NE * DM * FF * 2);     // 67 MB  [E][F][D]
  __hip_bfloat16* w2t = (__hip_bfloat16*)alloc((size_t)NE * FF * DM * 2);     // 67 MB  [E][D][F]
  __hip_bfloat16* Hb  = (__hip_bfloat16*)alloc((size_t)NE * CAP * FF * 2);    // 100 MB [E][CAP][F]
  int*   counts  = (int*)alloc(NE * sizeof(int));
  int*   tok_ids = (int*)alloc((size_t)NE * CAP * sizeof(int));
  float* gains   = (float*)alloc((size_t)NE * CAP * sizeof(float));
  (void)ws_size; (void)in_sizes; (void)n_in; (void)out_size;

  hipMemsetAsync(y, 0, (size_t)T_TOK * DM * sizeof(float), stream);
  hipMemsetAsync(counts, 0, NE * sizeof(int), stream);

  conv_x_kernel<<<(T_TOK * DM / 4 + 255) / 256, 256, 0, stream>>>(
      (const float4*)x, (ushort4*)xb, T_TOK * DM / 4);
  tconv_kernel<<<dim3(FF / 32, DM / 32, NE), dim3(32, 8), 0, stream>>>(W1, w1t, DM, FF);
  tconv_kernel<<<dim3(DM / 32, FF / 32, NE), dim3(32, 8), 0, stream>>>(W2, w2t, FF, DM);
  router_kernel<<<(T_TOK + 255) / 256, 256, 0, stream>>>(rw, counts, tok_ids, gains);
  pad_kernel<<<(NE * CAP + 255) / 256, 256, 0, stream>>>(counts, tok_ids, gains);

  moe_gemm<1><<<NE * (CAP / 128) * (FF / 128), 256, 0, stream>>>(
      xb, w1t, b1, counts, tok_ids, gains, Hb, nullptr);
  moe_gemm<2><<<NE * (CAP / 128) * (DM / 128), 256, 0, stream>>>(
      Hb, w2t, b2, counts, tok_ids, gains, nullptr, y);
}

// Round 2
// 351.913 us; speedup vs baseline: 1.1089x; 1.1089x over previous
//
#include <hip/hip_runtime.h>
#include <hip/hip_bf16.h>
#include <stdint.h>

// dims (fixed by the problem)
#define T_TOK 4096
#define NE    8
#define DM    1024
#define FF    4096
#define CAP   1536

typedef __attribute__((ext_vector_type(8))) __bf16 bf16x8;
typedef __attribute__((ext_vector_type(4))) float  f32x4;

__device__ __forceinline__ void gload_lds16(const void* gptr, void* lptr) {
  __builtin_amdgcn_global_load_lds(
      (__attribute__((address_space(1))) void*)(uintptr_t)gptr,
      (__attribute__((address_space(3))) void*)(uintptr_t)lptr,
      16, 0, 0);
}

// ---------------- small prep kernels ----------------

__global__ void conv_x_kernel(const float4* __restrict__ src, ushort4* __restrict__ dst, int n4) {
  int i = blockIdx.x * blockDim.x + threadIdx.x;
  if (i >= n4) return;
  float4 v = src[i];
  ushort4 o;
  o.x = __builtin_bit_cast(unsigned short, __float2bfloat16(v.x));
  o.y = __builtin_bit_cast(unsigned short, __float2bfloat16(v.y));
  o.z = __builtin_bit_cast(unsigned short, __float2bfloat16(v.z));
  o.w = __builtin_bit_cast(unsigned short, __float2bfloat16(v.w));
  dst[i] = o;
}

// transpose+convert: src f32 [B][R][C] -> dst bf16 [B][C][R], 64x64 tiles,
// ushort4 (8B) transposed stores for full-width write transactions.
__global__ __launch_bounds__(256)
void tconv_kernel(const float* __restrict__ src, __hip_bfloat16* __restrict__ dst,
                  int R, int C) {
  __shared__ float tile[64][65];
  const int b  = blockIdx.z;
  const int r0 = blockIdx.y * 64;
  const int c0 = blockIdx.x * 64;
  const float* s = src + (size_t)b * R * C;
  __hip_bfloat16* d = dst + (size_t)b * R * C;
  const int tid = threadIdx.x;
  const int tx = tid & 63, ty = tid >> 6;
#pragma unroll
  for (int rr = ty; rr < 64; rr += 4)
    tile[rr][tx] = s[(size_t)(r0 + rr) * C + c0 + tx];
  __syncthreads();
  const int lg = tid & 15;        // lane group -> 4 consecutive R per store
  const int cg = tid >> 4;        // 16 col groups
#pragma unroll
  for (int w = 0; w < 4; ++w) {
    const int cc = w * 16 + cg;
    const int r4 = lg * 4;
    ushort4 o;
    o.x = __builtin_bit_cast(unsigned short, __float2bfloat16(tile[r4 + 0][cc]));
    o.y = __builtin_bit_cast(unsigned short, __float2bfloat16(tile[r4 + 1][cc]));
    o.z = __builtin_bit_cast(unsigned short, __float2bfloat16(tile[r4 + 2][cc]));
    o.w = __builtin_bit_cast(unsigned short, __float2bfloat16(tile[r4 + 3][cc]));
    *(ushort4*)&d[(size_t)(c0 + cc) * R + r0 + r4] = o;
  }
}

__global__ void router_kernel(const float* __restrict__ rw, int* __restrict__ counts,
                              int* __restrict__ tok_ids, float* __restrict__ gains) {
  int t = blockIdx.x * blockDim.x + threadIdx.x;
  if (t >= T_TOK) return;
#pragma unroll
  for (int e = 0; e < NE; ++e) {
    float w = rw[t * NE + e];
    if (w > 0.f) {
      int pos = atomicAdd(&counts[e], 1);
      if (pos < CAP) {
        tok_ids[e * CAP + pos] = t;
        gains[e * CAP + pos]   = w;
      }
    }
  }
}

__global__ void pad_kernel(const int* __restrict__ counts, int* __restrict__ tok_ids,
                           float* __restrict__ gains) {
  int i = blockIdx.x * blockDim.x + threadIdx.x;
  if (i >= NE * CAP) return;
  int e = i / CAP, pos = i % CAP;
  int ne = min(counts[e], CAP);
  if (pos >= ne) { tok_ids[i] = 0; gains[i] = 0.f; }
}

// ---------------- grouped MFMA GEMM, pipelined 2-phase + LDS swizzle ----------------
// PASS 1:  H[e,c,:FF] = relu( gather(x)[c,:DM] @ W1t[e]^T + b1[e] )   (bf16 out)
// PASS 2:  y[tok(c)] += gain * ( H[e,c,:FF] @ W2t[e]^T + b2[e] )       (atomic f32)
// Tiles: BM=BN=128, BK=32, 256 threads (4 waves, 2x2 of 64x64), mfma 16x16x32 bf16.
// LDS double-buffered; STAGE(t+1) issued before compute(t); s_waitcnt vmcnt(4)
// (counted, never 0 in the main loop); XOR swizzle chunk^=((row>>1)&3) applied on
// the pre-swizzled GLOBAL source (gload_lds dest must stay linear) and on reads.

template <int PASS>
__global__ __launch_bounds__(256, 3)
void moe_gemm(const __hip_bfloat16* __restrict__ Asrc,
              const __hip_bfloat16* __restrict__ Bsrc,   // [E][NP][K] (B^T, k contiguous)
              const float* __restrict__ bias,            // [E][NP]
              const int* __restrict__ counts,
              const int* __restrict__ tok_ids,
              const float* __restrict__ gains,
              __hip_bfloat16* __restrict__ Hout,         // PASS1 out [E][CAP][FF]
              float* __restrict__ y)                     // PASS2 out [T][DM]
{
  constexpr int K  = (PASS == 1) ? DM : FF;
  constexpr int NP = (PASS == 1) ? FF : DM;
  constexpr int MT = CAP / 128;  // 12
  constexpr int NT = NP / 128;
  constexpr int KT = K / 32;     // K-tiles

  const int bid = blockIdx.x;
  const int e   = bid / (MT * NT);
  const int rem = bid % (MT * NT);
  const int mt  = rem / NT;
  const int nt  = rem % NT;

  const int Ne = min(counts[e], CAP);
  const int m0 = mt * 128;
  if (m0 >= Ne) return;
  const int n0 = nt * 128;

  __shared__ alignas(16) __hip_bfloat16 As[2 * 128 * 32];
  __shared__ alignas(16) __hip_bfloat16 Bs[2 * 128 * 32];

  const int tid  = threadIdx.x;
  const int lane = tid & 63;
  const int wid  = tid >> 6;
  const int wm   = wid >> 1;
  const int wn   = wid & 1;

  // staging map: thread tid -> LDS row = tid>>2 (+64 for second half), chunk = tid&3
  // source chunk pre-swizzled: cs = chunk ^ ((row>>1)&3)
  const int srow  = tid >> 2;
  const int cs    = ((tid & 3) ^ ((srow >> 1) & 3)) * 8;  // element offset in k

  const __hip_bfloat16 *aptr0, *aptr1;
  if (PASS == 1) {
    const int tok0 = tok_ids[e * CAP + m0 + srow];
    const int tok1 = tok_ids[e * CAP + m0 + 64 + srow];
    aptr0 = Asrc + (size_t)tok0 * DM + cs;
    aptr1 = Asrc + (size_t)tok1 * DM + cs;
  } else {
    aptr0 = Asrc + ((size_t)e * CAP + m0 + srow) * FF + cs;
    aptr1 = Asrc + ((size_t)e * CAP + m0 + 64 + srow) * FF + cs;
  }
  const __hip_bfloat16* bptr0 = Bsrc + ((size_t)e * NP + n0 + srow) * K + cs;
  const __hip_bfloat16* bptr1 = Bsrc + ((size_t)e * NP + n0 + 64 + srow) * K + cs;

  char* AsB = (char*)As;
  char* BsB = (char*)Bs;
  const int fr = lane & 15;
  const int fq = lane >> 4;
  // swizzled k-slice byte offset: independent of fragment row block (i*16, wm*64)
  const int kbyte = ((fq ^ ((fr >> 1) & 3)) << 4);

  f32x4 acc[4][4] = {};

#define STAGE(buf, kt)                                                        \
  do {                                                                        \
    gload_lds16(aptr0 + (kt) * 32, AsB + (buf) * 8192 + wid * 1024);          \
    gload_lds16(aptr1 + (kt) * 32, AsB + (buf) * 8192 + 4096 + wid * 1024);   \
    gload_lds16(bptr0 + (kt) * 32, BsB + (buf) * 8192 + wid * 1024);          \
    gload_lds16(bptr1 + (kt) * 32, BsB + (buf) * 8192 + 4096 + wid * 1024);   \
  } while (0)

#define COMPUTE(buf)                                                          \
  do {                                                                        \
    const char* Ab = AsB + (buf) * 8192;                                      \
    const char* Bb = BsB + (buf) * 8192;                                      \
    bf16x8 af[4], bfr[4];                                                     \
    _Pragma("unroll") for (int i = 0; i < 4; ++i)                             \
        af[i] = *(const bf16x8*)(Ab + (wm * 64 + i * 16 + fr) * 64 + kbyte);  \
    _Pragma("unroll") for (int j = 0; j < 4; ++j)                             \
        bfr[j] = *(const bf16x8*)(Bb + (wn * 64 + j * 16 + fr) * 64 + kbyte); \
    _Pragma("unroll") for (int i = 0; i < 4; ++i)                             \
        _Pragma("unroll") for (int j = 0; j < 4; ++j)                         \
            acc[i][j] = __builtin_amdgcn_mfma_f32_16x16x32_bf16(              \
                af[i], bfr[j], acc[i][j], 0, 0, 0);                           \
  } while (0)

  STAGE(0, 0);
  int cur = 0;
  for (int kt = 0; kt + 1 < KT; ++kt) {
    STAGE(cur ^ 1, kt + 1);                       // prefetch next tile
    asm volatile("s_waitcnt vmcnt(4)" ::: "memory");  // cur staged; next in flight
    __builtin_amdgcn_s_barrier();
    __builtin_amdgcn_sched_barrier(0);
    COMPUTE(cur);
    asm volatile("" ::: "memory");
    __builtin_amdgcn_s_barrier();                 // readers done before overwrite
    cur ^= 1;
  }
  asm volatile("s_waitcnt vmcnt(0)" ::: "memory");
  __builtin_amdgcn_s_barrier();
  __builtin_amdgcn_sched_barrier(0);
  COMPUTE(cur);

#undef STAGE
#undef COMPUTE

  const int colb = n0 + wn * 64 + fr;
  if (PASS == 1) {
#pragma unroll
    for (int j = 0; j < 4; ++j) {
      const float bv = bias[(size_t)e * NP + colb + j * 16];
#pragma unroll
      for (int i = 0; i < 4; ++i)
#pragma unroll
        for (int rr = 0; rr < 4; ++rr) {
          const int row = m0 + wm * 64 + i * 16 + fq * 4 + rr;
          float v = acc[i][j][rr] + bv;
          v = v > 0.f ? v : 0.f;
          Hout[((size_t)e * CAP + row) * FF + colb + j * 16] = __float2bfloat16(v);
        }
    }
  } else {
    float bv[4];
#pragma unroll
    for (int j = 0; j < 4; ++j) bv[j] = bias[(size_t)e * NP + colb + j * 16];
#pragma unroll
    for (int i = 0; i < 4; ++i)
#pragma unroll
      for (int rr = 0; rr < 4; ++rr) {
        const int row  = m0 + wm * 64 + i * 16 + fq * 4 + rr;
        const int slot = e * CAP + row;
        const float g  = gains[slot];
        if (g != 0.f) {
          const int tok = tok_ids[slot];
          float* yrow = y + (size_t)tok * DM + colb;
#pragma unroll
          for (int j = 0; j < 4; ++j)
            atomicAdd(yrow + j * 16, (acc[i][j][rr] + bv[j]) * g);
        }
      }
  }
}

// ---------------- launch ----------------

extern "C" void kernel_launch(void* const* d_in, const int* in_sizes, int n_in,
                              void* d_out, int out_size, void* d_ws, size_t ws_size,
                              hipStream_t stream) {
  const float* x  = (const float*)d_in[0];
  // d_in[1] = route_mask (bool) — unused: mask == (route_weight > 0)
  const float* rw = (const float*)d_in[2];
  const float* W1 = (const float*)d_in[3];
  const float* b1 = (const float*)d_in[4];
  const float* W2 = (const float*)d_in[5];
  const float* b2 = (const float*)d_in[6];
  float* y = (float*)d_out;

  char* ws = (char*)d_ws;
  size_t off = 0;
  auto alloc = [&](size_t bytes) {
    void* p = ws + off;
    off = (off + bytes + 255) & ~(size_t)255;
    return p;
  };
  __hip_bfloat16* xb  = (__hip_bfloat16*)alloc((size_t)T_TOK * DM * 2);       // 8.4 MB
  __hip_bfloat16* w1t = (__hip_bfloat16*)alloc((size_t)NE * DM * FF * 2);     // 67 MB  [E][F][D]
  __hip_bfloat16* w2t = (__hip_bfloat16*)alloc((size_t)NE * FF * DM * 2);     // 67 MB  [E][D][F]
  __hip_bfloat16* Hb  = (__hip_bfloat16*)alloc((size_t)NE * CAP * FF * 2);    // 100 MB [E][CAP][F]
  int*   counts  = (int*)alloc(NE * sizeof(int));
  int*   tok_ids = (int*)alloc((size_t)NE * CAP * sizeof(int));
  float* gains   = (float*)alloc((size_t)NE * CAP * sizeof(float));
  (void)ws_size; (void)in_sizes; (void)n_in; (void)out_size;

  hipMemsetAsync(y, 0, (size_t)T_TOK * DM * sizeof(float), stream);
  hipMemsetAsync(counts, 0, NE * sizeof(int), stream);

  conv_x_kernel<<<(T_TOK * DM / 4 + 255) / 256, 256, 0, stream>>>(
      (const float4*)x, (ushort4*)xb, T_TOK * DM / 4);
  tconv_kernel<<<dim3(FF / 64, DM / 64, NE), 256, 0, stream>>>(W1, w1t, DM, FF);
  tconv_kernel<<<dim3(DM / 64, FF / 64, NE), 256, 0, stream>>>(W2, w2t, FF, DM);
  router_kernel<<<(T_TOK + 255) / 256, 256, 0, stream>>>(rw, counts, tok_ids, gains);
  pad_kernel<<<(NE * CAP + 255) / 256, 256, 0, stream>>>(counts, tok_ids, gains);

  moe_gemm<1><<<NE * (CAP / 128) * (FF / 128), 256, 0, stream>>>(
      xb, w1t, b1, counts, tok_ids, gains, Hb, nullptr);
  moe_gemm<2><<<NE * (CAP / 128) * (DM / 128), 256, 0, stream>>>(
      Hb, w2t, b2, counts, tok_ids, gains, nullptr, y);
}